// Round 1
// baseline (938.947 us; speedup 1.0000x reference)
//
#include <hip/hip_runtime.h>

#define NUM_USERS 150000
#define NUM_ITEMS 140000
#define NUM_BRANDS 10000
#define N_NODES   300000          // users + items + brands
#define DIM       64
#define N_EDGES   1200000
#define OUT_ROWS  290000          // users + items

// ---------------------------------------------------------------------------
// init: h_cur = concat(user, item, brand); h_next = 0; out = ego[:OUT_ROWS]
// float4-vectorized over N_NODES*DIM elements.
// ---------------------------------------------------------------------------
__global__ void lgcn_init(const float* __restrict__ user,
                          const float* __restrict__ item,
                          const float* __restrict__ brand,
                          float* __restrict__ h_cur,
                          float* __restrict__ h_next,
                          float* __restrict__ out) {
    const int total4 = N_NODES * DIM / 4;          // 4.8M float4
    int idx = blockIdx.x * blockDim.x + threadIdx.x;
    if (idx >= total4) return;
    int e   = idx * 4;                             // float offset (< 19.2M, fits int)
    int row = e >> 6;                              // /DIM
    float4 v;
    if (row < NUM_USERS) {
        v = *reinterpret_cast<const float4*>(user + e);
    } else if (row < NUM_USERS + NUM_ITEMS) {
        v = *reinterpret_cast<const float4*>(item + (e - NUM_USERS * DIM));
    } else {
        v = *reinterpret_cast<const float4*>(brand + (e - (NUM_USERS + NUM_ITEMS) * DIM));
    }
    *reinterpret_cast<float4*>(h_cur + e) = v;
    *reinterpret_cast<float4*>(h_next + e) = make_float4(0.f, 0.f, 0.f, 0.f);
    if (row < OUT_ROWS) *reinterpret_cast<float4*>(out + e) = v;
}

// ---------------------------------------------------------------------------
// scatter: h_next[dst] += h_cur[src] * val   (one wave per edge, lane = dim)
// ---------------------------------------------------------------------------
__global__ void lgcn_scatter(const int*   __restrict__ src,
                             const int*   __restrict__ dst,
                             const float* __restrict__ vals,
                             const float* __restrict__ h_cur,
                             float*       __restrict__ h_next) {
    int t    = blockIdx.x * blockDim.x + threadIdx.x;
    int e    = t >> 6;
    int lane = t & 63;
    if (e >= N_EDGES) return;
    int   s = src[e];
    int   d = dst[e];
    float v = vals[e];
    float x = h_cur[s * DIM + lane] * v;
    atomicAdd(&h_next[d * DIM + lane], x);
}

// ---------------------------------------------------------------------------
// accum: out[:OUT_ROWS*DIM] += h_new (scaled by 0.25 on the last layer);
//        zero h_old so it can serve as the next layer's target.
// ---------------------------------------------------------------------------
__global__ void lgcn_accum(const float* __restrict__ h_new,
                           float*       __restrict__ h_old,
                           float*       __restrict__ out,
                           int          is_final) {
    const int total4 = N_NODES * DIM / 4;
    int idx = blockIdx.x * blockDim.x + threadIdx.x;
    if (idx >= total4) return;
    int e = idx * 4;
    if (e < OUT_ROWS * DIM) {
        float4 o = *reinterpret_cast<float4*>(out + e);
        float4 n = *reinterpret_cast<const float4*>(h_new + e);
        o.x += n.x; o.y += n.y; o.z += n.z; o.w += n.w;
        if (is_final) { o.x *= 0.25f; o.y *= 0.25f; o.z *= 0.25f; o.w *= 0.25f; }
        *reinterpret_cast<float4*>(out + e) = o;
    }
    if (!is_final) {
        *reinterpret_cast<float4*>(h_old + e) = make_float4(0.f, 0.f, 0.f, 0.f);
    }
}

extern "C" void kernel_launch(void* const* d_in, const int* in_sizes, int n_in,
                              void* d_out, int out_size, void* d_ws, size_t ws_size,
                              hipStream_t stream) {
    const float* user  = (const float*)d_in[0];
    const float* item  = (const float*)d_in[1];
    const float* brand = (const float*)d_in[2];
    const float* vals  = (const float*)d_in[3];
    const int*   src   = (const int*)d_in[4];
    const int*   dst   = (const int*)d_in[5];
    float* out = (float*)d_out;

    // workspace: two ping-pong h buffers, N_NODES*DIM floats each (76.8 MB)
    float* h0 = (float*)d_ws;
    float* h1 = h0 + (size_t)N_NODES * DIM;

    const int total4     = N_NODES * DIM / 4;
    const int elemBlocks = (total4 + 255) / 256;
    const int edgeBlocks = (N_EDGES * 64) / 256;   // 64 lanes per edge

    // h0 = ego, h1 = 0, out = ego[:OUT_ROWS]
    lgcn_init<<<elemBlocks, 256, 0, stream>>>(user, item, brand, h0, h1, out);

    // layer 1: h1 = A*h0 ; out += h1 ; h0 = 0
    lgcn_scatter<<<edgeBlocks, 256, 0, stream>>>(src, dst, vals, h0, h1);
    lgcn_accum<<<elemBlocks, 256, 0, stream>>>(h1, h0, out, 0);

    // layer 2: h0 = A*h1 ; out += h0 ; h1 = 0
    lgcn_scatter<<<edgeBlocks, 256, 0, stream>>>(src, dst, vals, h1, h0);
    lgcn_accum<<<elemBlocks, 256, 0, stream>>>(h0, h1, out, 0);

    // layer 3: h1 = A*h0 ; out = (out + h1) * 0.25
    lgcn_scatter<<<edgeBlocks, 256, 0, stream>>>(src, dst, vals, h0, h1);
    lgcn_accum<<<elemBlocks, 256, 0, stream>>>(h1, h0, out, 1);
}

// Round 2
// 625.683 us; speedup vs baseline: 1.5007x; 1.5007x over previous
//
#include <hip/hip_runtime.h>

#define NUM_USERS  150000
#define NUM_ITEMS  140000
#define NUM_BRANDS 10000
#define N_NODES    300000
#define DIM        64
#define N_EDGES    1200000
#define OUT_ROWS   290000          // users + items

#define CHUNK      1024            // elements per scan block
#define NB         ((N_NODES + CHUNK - 1) / CHUNK)   // 293 scan blocks

// ---------------------------------------------------------------------------
// init: h0 = concat(user,item,brand); out = ego[:OUT_ROWS]; counts = 0
// ---------------------------------------------------------------------------
__global__ void lgcn_init(const float* __restrict__ user,
                          const float* __restrict__ item,
                          const float* __restrict__ brand,
                          float* __restrict__ h0,
                          float* __restrict__ out,
                          int*   __restrict__ counts) {
    const int total4 = N_NODES * DIM / 4;          // 4.8M float4
    int idx = blockIdx.x * blockDim.x + threadIdx.x;
    if (idx >= total4) return;
    if (idx < N_NODES) counts[idx] = 0;
    int e   = idx * 4;
    int row = e >> 6;
    float4 v;
    if (row < NUM_USERS) {
        v = *reinterpret_cast<const float4*>(user + e);
    } else if (row < NUM_USERS + NUM_ITEMS) {
        v = *reinterpret_cast<const float4*>(item + (e - NUM_USERS * DIM));
    } else {
        v = *reinterpret_cast<const float4*>(brand + (e - (NUM_USERS + NUM_ITEMS) * DIM));
    }
    *reinterpret_cast<float4*>(h0 + e) = v;
    if (row < OUT_ROWS) *reinterpret_cast<float4*>(out + e) = v;
}

// ---------------------------------------------------------------------------
// histogram of destination degrees
// ---------------------------------------------------------------------------
__global__ void lgcn_hist(const int* __restrict__ dst, int* __restrict__ counts) {
    int e = blockIdx.x * blockDim.x + threadIdx.x;
    if (e >= N_EDGES) return;
    atomicAdd(&counts[dst[e]], 1);
}

// ---------------------------------------------------------------------------
// scan phase 1: per-1024-chunk exclusive scan (256 thr x 4 elem), chunk sums
// ---------------------------------------------------------------------------
__global__ void lgcn_scan_p1(const int* __restrict__ counts,
                             int* __restrict__ rowptr,
                             int* __restrict__ blockSums) {
    __shared__ int ts[256];
    int b    = blockIdx.x;
    int base = b * CHUNK;
    int t    = threadIdx.x;
    int c[4];
    int s = 0;
#pragma unroll
    for (int i = 0; i < 4; ++i) {
        int g = base + t * 4 + i;
        c[i] = (g < N_NODES) ? counts[g] : 0;
        s += c[i];
    }
    ts[t] = s;
    __syncthreads();
    // Hillis-Steele inclusive scan over 256 thread-sums
    for (int off = 1; off < 256; off <<= 1) {
        int v = (t >= off) ? ts[t - off] : 0;
        __syncthreads();
        ts[t] += v;
        __syncthreads();
    }
    int run = ts[t] - s;     // exclusive prefix of this thread's 4-group
#pragma unroll
    for (int i = 0; i < 4; ++i) {
        int g = base + t * 4 + i;
        if (g < N_NODES) rowptr[g] = run;
        run += c[i];
    }
    if (t == 255) blockSums[b] = ts[255];
}

// ---------------------------------------------------------------------------
// scan phase 2: single block exclusive-scans the NB (=293) chunk sums
// ---------------------------------------------------------------------------
__global__ void lgcn_scan_p2(int* __restrict__ blockSums) {
    __shared__ int sh[512];
    int t = threadIdx.x;
    int v = (t < NB) ? blockSums[t] : 0;
    sh[t] = v;
    __syncthreads();
    for (int off = 1; off < 512; off <<= 1) {
        int u = (t >= off) ? sh[t - off] : 0;
        __syncthreads();
        sh[t] += u;
        __syncthreads();
    }
    if (t < NB) blockSums[t] = sh[t] - v;   // exclusive
}

// ---------------------------------------------------------------------------
// scan phase 3: add chunk offsets; cursor = rowptr; rowptr[N_NODES] = N_EDGES
// ---------------------------------------------------------------------------
__global__ void lgcn_scan_p3(int* __restrict__ rowptr,
                             const int* __restrict__ blockSums,
                             int* __restrict__ cursor) {
    int b    = blockIdx.x;
    int base = b * CHUNK;
    int t    = threadIdx.x;
    int off  = blockSums[b];
#pragma unroll
    for (int i = 0; i < 4; ++i) {
        int g = base + t * 4 + i;
        if (g < N_NODES) {
            int r = rowptr[g] + off;
            rowptr[g] = r;
            cursor[g] = r;
        }
    }
    if (b == 0 && t == 0) rowptr[N_NODES] = N_EDGES;
}

// ---------------------------------------------------------------------------
// place edges into dst-sorted CSR; packed (src, val) as uint2 -> dwordx2
// ---------------------------------------------------------------------------
__global__ void lgcn_place(const int*   __restrict__ src,
                           const int*   __restrict__ dst,
                           const float* __restrict__ vals,
                           int*  __restrict__ cursor,
                           uint2* __restrict__ csr) {
    int e = blockIdx.x * blockDim.x + threadIdx.x;
    if (e >= N_EDGES) return;
    int d   = dst[e];
    int pos = atomicAdd(&cursor[d], 1);
    uint2 rec;
    rec.x = (unsigned)src[e];
    rec.y = __float_as_uint(vals[e]);
    csr[pos] = rec;
}

// ---------------------------------------------------------------------------
// gather SpMM: one wave per dst node, lane = dim. No atomics.
// Fused: out += row (layers 1,2); out = (out+row)*0.25 (final layer).
// ---------------------------------------------------------------------------
template <int FINAL>
__global__ void lgcn_gather(const int*  __restrict__ rowptr,
                            const uint2* __restrict__ csr,
                            const float* __restrict__ h_cur,
                            float*       __restrict__ h_next,
                            float*       __restrict__ out) {
    int t = blockIdx.x * blockDim.x + threadIdx.x;   // == d*64 + lane
    int d    = t >> 6;
    int lane = t & 63;
    if (d >= N_NODES) return;
    int beg = rowptr[d];
    int end = rowptr[d + 1];
    float sum = 0.f;
    for (int j = beg; j < end; ++j) {
        uint2 rec = csr[j];                          // wave-uniform -> broadcast
        float v = __uint_as_float(rec.y);
        sum = fmaf(h_cur[((int)rec.x << 6) + lane], v, sum);
    }
    if (!FINAL) h_next[t] = sum;
    if (d < OUT_ROWS) {
        if (FINAL) out[t] = (out[t] + sum) * 0.25f;
        else       out[t] += sum;
    }
}

extern "C" void kernel_launch(void* const* d_in, const int* in_sizes, int n_in,
                              void* d_out, int out_size, void* d_ws, size_t ws_size,
                              hipStream_t stream) {
    const float* user  = (const float*)d_in[0];
    const float* item  = (const float*)d_in[1];
    const float* brand = (const float*)d_in[2];
    const float* vals  = (const float*)d_in[3];
    const int*   src   = (const int*)d_in[4];
    const int*   dst   = (const int*)d_in[5];
    float* out = (float*)d_out;

    // workspace layout (32-bit words); keep csr 8B-aligned
    size_t W = 0;
    float* h0 = (float*)d_ws;                 W += (size_t)N_NODES * DIM;
    float* h1 = (float*)d_ws + W;             W += (size_t)N_NODES * DIM;   // even offset
    uint2* csr = (uint2*)((float*)d_ws + W);  W += (size_t)N_EDGES * 2;
    int* rowptr    = (int*)((float*)d_ws + W); W += N_NODES + 2;            // +pad
    int* counts    = (int*)((float*)d_ws + W); W += N_NODES;
    int* cursor    = (int*)((float*)d_ws + W); W += N_NODES;
    int* blockSums = (int*)((float*)d_ws + W); W += 512;
    (void)ws_size; (void)n_in; (void)in_sizes; (void)out_size;

    const int total4     = N_NODES * DIM / 4;
    const int elemBlocks = (total4 + 255) / 256;        // 18750
    const int edgeBlocks = (N_EDGES + 255) / 256;       // 4688
    const int nodeBlocks = (N_NODES * DIM) / 256;       // 75000 (wave per node)

    // ego init + counts zero
    lgcn_init<<<elemBlocks, 256, 0, stream>>>(user, item, brand, h0, out, counts);

    // build dst-sorted CSR
    lgcn_hist   <<<edgeBlocks, 256, 0, stream>>>(dst, counts);
    lgcn_scan_p1<<<NB, 256, 0, stream>>>(counts, rowptr, blockSums);
    lgcn_scan_p2<<<1, 512, 0, stream>>>(blockSums);
    lgcn_scan_p3<<<NB, 256, 0, stream>>>(rowptr, blockSums, cursor);
    lgcn_place  <<<edgeBlocks, 256, 0, stream>>>(src, dst, vals, cursor, csr);

    // 3 atomic-free SpMM layers with fused residual accumulation
    lgcn_gather<0><<<nodeBlocks, 256, 0, stream>>>(rowptr, csr, h0, h1, out);
    lgcn_gather<0><<<nodeBlocks, 256, 0, stream>>>(rowptr, csr, h1, h0, out);
    lgcn_gather<1><<<nodeBlocks, 256, 0, stream>>>(rowptr, csr, h0, h1, out);
}

// Round 3
// 387.690 us; speedup vs baseline: 2.4219x; 1.6139x over previous
//
#include <hip/hip_runtime.h>

#define NUM_USERS  150000
#define NUM_ITEMS  140000
#define NUM_BRANDS 10000
#define N_NODES    300000
#define DIM        64
#define N_EDGES    1200000
#define OUT_ROWS   290000          // users + items

#define CHUNK      1024            // elements per scan block
#define NB         ((N_NODES + CHUNK - 1) / CHUNK)   // 293 scan blocks

// ---------------------------------------------------------------------------
// init: h0 = concat(user,item,brand); out = ego[:OUT_ROWS]; counts = 0
// ---------------------------------------------------------------------------
__global__ void lgcn_init(const float* __restrict__ user,
                          const float* __restrict__ item,
                          const float* __restrict__ brand,
                          float* __restrict__ h0,
                          float* __restrict__ out,
                          int*   __restrict__ counts) {
    const int total4 = N_NODES * DIM / 4;          // 4.8M float4
    int idx = blockIdx.x * blockDim.x + threadIdx.x;
    if (idx >= total4) return;
    if (idx < N_NODES) counts[idx] = 0;
    int e   = idx * 4;
    int row = e >> 6;
    float4 v;
    if (row < NUM_USERS) {
        v = *reinterpret_cast<const float4*>(user + e);
    } else if (row < NUM_USERS + NUM_ITEMS) {
        v = *reinterpret_cast<const float4*>(item + (e - NUM_USERS * DIM));
    } else {
        v = *reinterpret_cast<const float4*>(brand + (e - (NUM_USERS + NUM_ITEMS) * DIM));
    }
    *reinterpret_cast<float4*>(h0 + e) = v;
    if (row < OUT_ROWS) *reinterpret_cast<float4*>(out + e) = v;
}

// ---------------------------------------------------------------------------
// histogram of destination degrees
// ---------------------------------------------------------------------------
__global__ void lgcn_hist(const int* __restrict__ dst, int* __restrict__ counts) {
    int e = blockIdx.x * blockDim.x + threadIdx.x;
    if (e >= N_EDGES) return;
    atomicAdd(&counts[dst[e]], 1);
}

// ---------------------------------------------------------------------------
// scan phase 1: per-1024-chunk exclusive scan (256 thr x 4 elem), chunk sums
// ---------------------------------------------------------------------------
__global__ void lgcn_scan_p1(const int* __restrict__ counts,
                             int* __restrict__ rowptr,
                             int* __restrict__ blockSums) {
    __shared__ int ts[256];
    int b    = blockIdx.x;
    int base = b * CHUNK;
    int t    = threadIdx.x;
    int c[4];
    int s = 0;
#pragma unroll
    for (int i = 0; i < 4; ++i) {
        int g = base + t * 4 + i;
        c[i] = (g < N_NODES) ? counts[g] : 0;
        s += c[i];
    }
    ts[t] = s;
    __syncthreads();
    for (int off = 1; off < 256; off <<= 1) {
        int v = (t >= off) ? ts[t - off] : 0;
        __syncthreads();
        ts[t] += v;
        __syncthreads();
    }
    int run = ts[t] - s;     // exclusive prefix of this thread's 4-group
#pragma unroll
    for (int i = 0; i < 4; ++i) {
        int g = base + t * 4 + i;
        if (g < N_NODES) rowptr[g] = run;
        run += c[i];
    }
    if (t == 255) blockSums[b] = ts[255];
}

// ---------------------------------------------------------------------------
// scan phase 2: single block exclusive-scans the NB (=293) chunk sums
// ---------------------------------------------------------------------------
__global__ void lgcn_scan_p2(int* __restrict__ blockSums) {
    __shared__ int sh[512];
    int t = threadIdx.x;
    int v = (t < NB) ? blockSums[t] : 0;
    sh[t] = v;
    __syncthreads();
    for (int off = 1; off < 512; off <<= 1) {
        int u = (t >= off) ? sh[t - off] : 0;
        __syncthreads();
        sh[t] += u;
        __syncthreads();
    }
    if (t < NB) blockSums[t] = sh[t] - v;   // exclusive
}

// ---------------------------------------------------------------------------
// scan phase 3: add chunk offsets; cursor = rowptr; rowptr[N_NODES] = N_EDGES
// ---------------------------------------------------------------------------
__global__ void lgcn_scan_p3(int* __restrict__ rowptr,
                             const int* __restrict__ blockSums,
                             int* __restrict__ cursor) {
    int b    = blockIdx.x;
    int base = b * CHUNK;
    int t    = threadIdx.x;
    int off  = blockSums[b];
#pragma unroll
    for (int i = 0; i < 4; ++i) {
        int g = base + t * 4 + i;
        if (g < N_NODES) {
            int r = rowptr[g] + off;
            rowptr[g] = r;
            cursor[g] = r;
        }
    }
    if (b == 0 && t == 0) rowptr[N_NODES] = N_EDGES;
}

// ---------------------------------------------------------------------------
// place edges into dst-sorted CSR; packed (src, val) as uint2 -> dwordx2
// ---------------------------------------------------------------------------
__global__ void lgcn_place(const int*   __restrict__ src,
                           const int*   __restrict__ dst,
                           const float* __restrict__ vals,
                           int*  __restrict__ cursor,
                           uint2* __restrict__ csr) {
    int e = blockIdx.x * blockDim.x + threadIdx.x;
    if (e >= N_EDGES) return;
    int d   = dst[e];
    int pos = atomicAdd(&cursor[d], 1);
    uint2 rec;
    rec.x = (unsigned)src[e];
    rec.y = __float_as_uint(vals[e]);
    csr[pos] = rec;
}

// ---------------------------------------------------------------------------
// gather SpMM: 16 lanes per dst node (float4 each), 4 nodes per wave.
// 2-deep software pipeline: prefetch csr[j+2] and row j+1 while fma-ing row j.
// Fused: out += row (layers 1,2); out = (out+row)*0.25 (final layer).
// ---------------------------------------------------------------------------
template <int FINAL>
__global__ void lgcn_gather(const int*   __restrict__ rowptr,
                            const uint2* __restrict__ csr,
                            const float* __restrict__ h_cur,
                            float*       __restrict__ h_next,
                            float*       __restrict__ out) {
    int t    = blockIdx.x * blockDim.x + threadIdx.x;   // node*16 + q
    int node = t >> 4;
    int q    = t & 15;
    int beg = rowptr[node];
    int end = rowptr[node + 1];
    float4 sum = make_float4(0.f, 0.f, 0.f, 0.f);
    if (beg < end) {
        uint2 rec0 = csr[beg];
        uint2 rec1 = csr[(beg + 1 < end) ? beg + 1 : beg];
        float4 r0 = *(reinterpret_cast<const float4*>(h_cur + ((long)rec0.x << 6)) + q);
        for (int j = beg; j < end; ++j) {
            int jn = j + 2 < end ? j + 2 : end - 1;
            uint2 rec2 = csr[jn];                       // prefetch rec, 2 ahead
            float4 r1 = *(reinterpret_cast<const float4*>(h_cur + ((long)rec1.x << 6)) + q);
            float v = __uint_as_float(rec0.y);
            sum.x = fmaf(r0.x, v, sum.x);
            sum.y = fmaf(r0.y, v, sum.y);
            sum.z = fmaf(r0.z, v, sum.z);
            sum.w = fmaf(r0.w, v, sum.w);
            rec0 = rec1; rec1 = rec2; r0 = r1;
        }
    }
    int off = t * 4;                                    // == node*64 + q*4
    if (!FINAL) *reinterpret_cast<float4*>(h_next + off) = sum;
    if (node < OUT_ROWS) {
        float4 o = *reinterpret_cast<float4*>(out + off);
        if (FINAL) {
            o.x = (o.x + sum.x) * 0.25f;
            o.y = (o.y + sum.y) * 0.25f;
            o.z = (o.z + sum.z) * 0.25f;
            o.w = (o.w + sum.w) * 0.25f;
        } else {
            o.x += sum.x; o.y += sum.y; o.z += sum.z; o.w += sum.w;
        }
        *reinterpret_cast<float4*>(out + off) = o;
    }
}

extern "C" void kernel_launch(void* const* d_in, const int* in_sizes, int n_in,
                              void* d_out, int out_size, void* d_ws, size_t ws_size,
                              hipStream_t stream) {
    const float* user  = (const float*)d_in[0];
    const float* item  = (const float*)d_in[1];
    const float* brand = (const float*)d_in[2];
    const float* vals  = (const float*)d_in[3];
    const int*   src   = (const int*)d_in[4];
    const int*   dst   = (const int*)d_in[5];
    float* out = (float*)d_out;

    // workspace layout (32-bit words); keep csr 8B-aligned
    size_t W = 0;
    float* h0 = (float*)d_ws;                  W += (size_t)N_NODES * DIM;
    float* h1 = (float*)d_ws + W;              W += (size_t)N_NODES * DIM;
    uint2* csr = (uint2*)((float*)d_ws + W);   W += (size_t)N_EDGES * 2;
    int* rowptr    = (int*)((float*)d_ws + W); W += N_NODES + 2;
    int* counts    = (int*)((float*)d_ws + W); W += N_NODES;
    int* cursor    = (int*)((float*)d_ws + W); W += N_NODES;
    int* blockSums = (int*)((float*)d_ws + W); W += 512;
    (void)ws_size; (void)n_in; (void)in_sizes; (void)out_size;

    const int total4      = N_NODES * DIM / 4;
    const int elemBlocks  = (total4 + 255) / 256;        // 18750
    const int edgeBlocks  = (N_EDGES + 255) / 256;       // 4688
    const int gatherBlocks = (N_NODES * 16) / 256;       // 18750 (16 thr/node)

    // ego init + counts zero
    lgcn_init<<<elemBlocks, 256, 0, stream>>>(user, item, brand, h0, out, counts);

    // build dst-sorted CSR
    lgcn_hist   <<<edgeBlocks, 256, 0, stream>>>(dst, counts);
    lgcn_scan_p1<<<NB, 256, 0, stream>>>(counts, rowptr, blockSums);
    lgcn_scan_p2<<<1, 512, 0, stream>>>(blockSums);
    lgcn_scan_p3<<<NB, 256, 0, stream>>>(rowptr, blockSums, cursor);
    lgcn_place  <<<edgeBlocks, 256, 0, stream>>>(src, dst, vals, cursor, csr);

    // 3 atomic-free SpMM layers with fused residual accumulation
    lgcn_gather<0><<<gatherBlocks, 256, 0, stream>>>(rowptr, csr, h0, h1, out);
    lgcn_gather<0><<<gatherBlocks, 256, 0, stream>>>(rowptr, csr, h1, h0, out);
    lgcn_gather<1><<<gatherBlocks, 256, 0, stream>>>(rowptr, csr, h0, h1, out);
}